// Round 5
// baseline (627.164 us; speedup 1.0000x reference)
//
#include <hip/hip_runtime.h>
#include <math.h>
#include <limits.h>

#define BOX   256
#define KTAPS 9
#define HALF  4
#define NPTS  50000
#define LATD  10
#define NEUR  32
#define NLAY  3
#define BATCH 16

#define ATPB  256
#define ABLKX ((NPTS + ATPB - 1)/ATPB)     // 196

#define BTPB  256
#define BPPT  8
#define BPTS  (BTPB*BPPT)                  // 2048 points per splat block
#define BBLKX ((NPTS + BPTS - 1)/BPTS)     // 25
#define TILE_CAP 9600                      // 37.5 KB LDS splat window
#define NTILES (BATCH*BBLKX)               // 400

#define IMG_ELEMS (BATCH*BOX*BOX)          // 1,048,576
#define OFF_IMG2  (IMG_ELEMS)
#define OFF_PROJ  (2*IMG_ELEMS)
#define OFF_POS   (OFF_PROJ + BATCH*NPTS*2)
#define OFF_RES   (OFF_POS  + BATCH*NPTS*3)

__device__ __forceinline__ float fast_tanh(float x) {
    return 1.0f - 2.0f / (__expf(2.0f * x) + 1.0f);
}

// ---------------- kernel A: per-point MLP + outputs ----------------
__global__ __launch_bounds__(ATPB) void mlp_fwd(
    const float* __restrict__ z, const float* __restrict__ r,
    const float* __restrict__ pos_param,
    const float* __restrict__ lin0_w, const float* __restrict__ deform_w,
    const float* __restrict__ deform_b, const float* __restrict__ lin1a_w,
    const float* __restrict__ lin1b_w, const int* __restrict__ dflag,
    float* __restrict__ out)
{
    __shared__ float s_zpart[NEUR];
    const int b = blockIdx.y, tid = threadIdx.x;

    if (tid < NEUR) {
        float acc = 0.f;
        #pragma unroll
        for (int j = 0; j < LATD-1; j++)
            acc = fmaf(lin0_w[tid*12 + 3 + j], z[b*LATD + j], acc);
        s_zpart[tid] = acc;
    }
    __syncthreads();

    const int n = blockIdx.x*ATPB + tid;
    if (n >= NPTS) return;
    const int dd = *dflag;

    const float r00 = r[b*9+0], r01 = r[b*9+1];
    const float r10 = r[b*9+3], r11 = r[b*9+4];
    const float r20 = r[b*9+6], r21 = r[b*9+7];

    const float p0 = pos_param[n*3+0];
    const float p1 = pos_param[n*3+1];
    const float p2 = pos_param[n*3+2];

    float res0 = 0.f, res1 = 0.f, res2 = 0.f;
    if (dd > 0) {
        float h[NEUR], nh[NEUR];
        #pragma unroll
        for (int o = 0; o < NEUR; o++) {
            float acc = s_zpart[o];
            acc = fmaf(lin0_w[o*12+0], p0, acc);
            acc = fmaf(lin0_w[o*12+1], p1, acc);
            acc = fmaf(lin0_w[o*12+2], p2, acc);
            h[o] = acc;
        }
        #pragma unroll 1
        for (int l = 0; l < NLAY; l++) {
            const float* __restrict__ W  = deform_w + l*NEUR*NEUR;
            const float* __restrict__ bb = deform_b + l*NEUR;
            #pragma unroll
            for (int o = 0; o < NEUR; o++) {
                float acc = bb[o];
                #pragma unroll
                for (int j = 0; j < NEUR; j++)
                    acc = fmaf(W[o*NEUR + j], h[j], acc);
                nh[o] = fmaxf(acc, 0.f) + h[o];
            }
            #pragma unroll
            for (int o = 0; o < NEUR; o++) h[o] = nh[o];
        }
        float t0 = 0.f, t1 = 0.f, t2 = 0.f;
        #pragma unroll
        for (int j = 0; j < NEUR; j++) {
            t0 = fmaf(lin1a_w[0*NEUR + j], h[j], t0);
            t1 = fmaf(lin1a_w[1*NEUR + j], h[j], t1);
            t2 = fmaf(lin1a_w[2*NEUR + j], h[j], t2);
        }
        t0 = fast_tanh(t0); t1 = fast_tanh(t1); t2 = fast_tanh(t2);
        res0 = fmaf(t0, lin1b_w[0], fmaf(t1, lin1b_w[1], t2*lin1b_w[2]));
        res1 = fmaf(t0, lin1b_w[3], fmaf(t1, lin1b_w[4], t2*lin1b_w[5]));
        res2 = fmaf(t0, lin1b_w[6], fmaf(t1, lin1b_w[7], t2*lin1b_w[8]));
    }

    const float pos0 = p0 + res0, pos1 = p1 + res1, pos2 = p2 + res2;
    const float proj0 = fmaf(pos0, r00, fmaf(pos1, r10, pos2*r20));
    const float proj1 = fmaf(pos0, r01, fmaf(pos1, r11, pos2*r21));

    const long long bn = (long long)b*NPTS + n;
    out[OFF_PROJ + bn*2 + 0] = proj0;
    out[OFF_PROJ + bn*2 + 1] = proj1;
    out[OFF_POS  + bn*3 + 0] = pos0;
    out[OFF_POS  + bn*3 + 1] = pos1;
    out[OFF_POS  + bn*3 + 2] = pos2;
    out[OFF_RES  + bn*3 + 0] = res0;
    out[OFF_RES  + bn*3 + 1] = res1;
    out[OFF_RES  + bn*3 + 2] = res2;
}

// ------------- kernel B: splat into private LDS window -> scratch -------------
__global__ __launch_bounds__(BTPB) void splat(
    const float* __restrict__ z, const float* __restrict__ amp,
    const float* __restrict__ linamp_w, const float* __restrict__ linamp_b,
    float* __restrict__ out, float* __restrict__ ws_tiles, int* __restrict__ ws_hdr)
{
    __shared__ float tile[TILE_CAP];
    __shared__ int s_lo0, s_hi0, s_lo1, s_hi1;

    const int b = blockIdx.y, tid = threadIdx.x;
    if (tid == 0) { s_lo0 = INT_MAX; s_hi0 = INT_MIN; s_lo1 = INT_MAX; s_hi1 = INT_MIN; }
    for (int i = tid; i < TILE_CAP; i += BTPB) tile[i] = 0.f;

    const float ampv  = amp[0];
    const float zlast = z[b*LATD + LATD-1];
    const float* __restrict__ proj = out + OFF_PROJ;
    const int base = blockIdx.x * BPTS;

    float spx[BPPT], spy[BPPT], sa[BPPT];
    int lmin0 = INT_MAX, lmax0 = INT_MIN, lmin1 = INT_MAX, lmax1 = INT_MIN;

    #pragma unroll
    for (int p = 0; p < BPPT; p++) {
        sa[p] = 0.f; spx[p] = 0.f; spy[p] = 0.f;
        const int n = base + p*BTPB + tid;
        if (n >= NPTS) continue;
        const long long bn = (long long)b*NPTS + n;
        const float proj0 = proj[bn*2 + 0];
        const float proj1 = proj[bn*2 + 1];
        const float lo = fmaf(zlast, linamp_w[n], linamp_b[n]);
        sa[p] = ampv / (1.0f + __expf(-lo));

        const float px0 = (proj0 + 0.5f) * (float)(BOX-1);
        const float px1 = (proj1 + 0.5f) * (float)(BOX-1);
        spx[p] = px0; spy[p] = px1;
        const float c0 = floorf(px0 + 0.5f);
        const float c1 = floorf(px1 + 0.5f);
        const int il0 = (int)fminf(fmaxf(c0 - (float)HALF, 0.f), (float)(BOX-1));
        const int ih0 = (int)fminf(fmaxf(c0 + (float)HALF, 0.f), (float)(BOX-1));
        const int il1 = (int)fminf(fmaxf(c1 - (float)HALF, 0.f), (float)(BOX-1));
        const int ih1 = (int)fminf(fmaxf(c1 + (float)HALF, 0.f), (float)(BOX-1));
        lmin0 = min(lmin0, il0); lmax0 = max(lmax0, ih0);
        lmin1 = min(lmin1, il1); lmax1 = max(lmax1, ih1);
    }
    __syncthreads();   // tile zeroed; bounds vars initialized
    if (lmin0 != INT_MAX) {
        atomicMin(&s_lo0, lmin0); atomicMax(&s_hi0, lmax0);
        atomicMin(&s_lo1, lmin1); atomicMax(&s_hi1, lmax1);
    }
    __syncthreads();

    const int lo0 = s_lo0, lo1 = s_lo1;
    const int W0 = s_hi0 - lo0 + 1, W1 = s_hi1 - lo1 + 1;
    const bool lds_ok = (s_hi0 >= lo0) && (W0 * W1 <= TILE_CAP);
    float* img = out + (size_t)b*BOX*BOX;
    const float inv2s2 = 1.0f/(2.0f*1.5f*1.5f);

    #pragma unroll 1
    for (int p = 0; p < BPPT; p++) {
        const float aamp = sa[p];
        if (aamp == 0.f) continue;
        const float px0 = spx[p], px1 = spy[p];
        const float c0 = floorf(px0 + 0.5f);
        const float c1 = floorf(px1 + 0.5f);

        float w0a[KTAPS], w1a[KTAPS];
        int   i0a[KTAPS], i1a[KTAPS];
        #pragma unroll
        for (int k = 0; k < KTAPS; k++) {
            float g0 = c0 + (float)(k - HALF);
            float d0 = g0 - px0;
            float ww0 = __expf(-d0*d0*inv2s2);
            if (g0 < 0.f || g0 > (float)(BOX-1)) ww0 = 0.f;
            w0a[k] = ww0;
            i0a[k] = (int)fminf(fmaxf(g0, 0.f), (float)(BOX-1));

            float g1 = c1 + (float)(k - HALF);
            float d1 = g1 - px1;
            float ww1 = __expf(-d1*d1*inv2s2);
            if (g1 < 0.f || g1 > (float)(BOX-1)) ww1 = 0.f;
            w1a[k] = ww1;
            i1a[k] = (int)fminf(fmaxf(g1, 0.f), (float)(BOX-1));
        }

        if (lds_ok) {
            #pragma unroll
            for (int ky = 0; ky < KTAPS; ky++) {
                const float ay = aamp * w0a[ky];
                const int rbase = (i0a[ky] - lo0)*W1 - lo1;
                #pragma unroll
                for (int kx = 0; kx < KTAPS; kx++)
                    atomicAdd(&tile[rbase + i1a[kx]], ay * w1a[kx]);
            }
        } else {
            #pragma unroll
            for (int ky = 0; ky < KTAPS; ky++) {
                const float ay = aamp * w0a[ky];
                float* rowp = img + i0a[ky]*BOX;
                #pragma unroll
                for (int kx = 0; kx < KTAPS; kx++)
                    atomicAdd(&rowp[i1a[kx]], ay * w1a[kx]);
            }
        }
    }

    __syncthreads();

    // ---- flush window to scratch with plain coalesced stores ----
    const int tb = b*BBLKX + blockIdx.x;
    if (lds_ok) {
        float* __restrict__ dst = ws_tiles + (size_t)tb*TILE_CAP;
        const int W = W0 * W1;
        for (int idx = tid; idx < W; idx += BTPB) dst[idx] = tile[idx];
        if (tid == 0) {
            ws_hdr[tb*4+0] = lo0; ws_hdr[tb*4+1] = lo1;
            ws_hdr[tb*4+2] = W0;  ws_hdr[tb*4+3] = W1;
        }
    } else {
        if (tid == 0) {
            ws_hdr[tb*4+0] = 0; ws_hdr[tb*4+1] = 0;
            ws_hdr[tb*4+2] = 0; ws_hdr[tb*4+3] = 0;   // W0=0 -> reduce skips
        }
    }
}

// ------------- kernel C: reduce scratch windows -> img + img2 -------------
__global__ __launch_bounds__(256) void reduce_img(
    const float* __restrict__ ws_tiles, const int* __restrict__ ws_hdr,
    float* __restrict__ out)
{
    const int b = blockIdx.y;
    const int p = blockIdx.x*256 + threadIdx.x;   // one full image row per block
    const int y = p >> 8, x = p & 255;

    float sum = 0.f;
    #pragma unroll 1
    for (int blk = 0; blk < BBLKX; blk++) {
        const int tb = b*BBLKX + blk;
        const int lo0 = ws_hdr[tb*4+0], lo1 = ws_hdr[tb*4+1];
        const int W0  = ws_hdr[tb*4+2], W1  = ws_hdr[tb*4+3];
        const int ry = y - lo0, rx = x - lo1;
        if (ry >= 0 && ry < W0 && rx >= 0 && rx < W1)
            sum += ws_tiles[(size_t)tb*TILE_CAP + ry*W1 + rx];
    }
    const size_t ip = (size_t)b*BOX*BOX + p;
    const float v = out[ip] + sum;        // base = memset 0 + any fallback atomics
    out[ip] = v;
    out[OFF_IMG2 + ip] = v;
}

extern "C" void kernel_launch(void* const* d_in, const int* in_sizes, int n_in,
                              void* d_out, int out_size, void* d_ws, size_t ws_size,
                              hipStream_t stream)
{
    const float* z        = (const float*)d_in[0];
    const float* r        = (const float*)d_in[1];
    const float* posp     = (const float*)d_in[2];
    const float* amp      = (const float*)d_in[3];
    const float* lin0_w   = (const float*)d_in[4];
    const float* deform_w = (const float*)d_in[5];
    const float* deform_b = (const float*)d_in[6];
    const float* lin1a_w  = (const float*)d_in[7];
    const float* lin1b_w  = (const float*)d_in[8];
    const float* linamp_w = (const float*)d_in[9];
    const float* linamp_b = (const float*)d_in[10];
    const int*   dflag    = (const int*)d_in[11];
    float* out = (float*)d_out;

    float* ws_tiles = (float*)d_ws;                               // 400*9600 floats
    int*   ws_hdr   = (int*)(ws_tiles + (size_t)NTILES*TILE_CAP); // 400*4 ints

    hipMemsetAsync(out, 0, (size_t)IMG_ELEMS*sizeof(float), stream);

    dim3 gridA(ABLKX, BATCH);
    mlp_fwd<<<gridA, ATPB, 0, stream>>>(z, r, posp, lin0_w, deform_w, deform_b,
                                        lin1a_w, lin1b_w, dflag, out);

    dim3 gridB(BBLKX, BATCH);
    splat<<<gridB, BTPB, 0, stream>>>(z, amp, linamp_w, linamp_b, out, ws_tiles, ws_hdr);

    dim3 gridC(BOX*BOX/256, BATCH);
    reduce_img<<<gridC, 256, 0, stream>>>(ws_tiles, ws_hdr, out);
}